// Round 8
// baseline (132.266 us; speedup 1.0000x reference)
//
#include <hip/hip_runtime.h>
#include <hip/hip_bf16.h>

// MHA: B=2 T=2048 H=1024 NH=16 HD=64. All matmuls via bf16 MFMA 16x16x32.
#define Bb 2
#define Tt 2048
#define Hh 1024
#define NHh 16

typedef short bf16x8 __attribute__((ext_vector_type(8)));
typedef float f32x4 __attribute__((ext_vector_type(4)));
typedef unsigned short u16;
typedef unsigned int u32;
typedef u16 u16x4v __attribute__((ext_vector_type(4)));
typedef u32 u32x2v __attribute__((ext_vector_type(2)));

// 0.125 * log2(e): folded into w_q/b_q so softmax runs in exp2 domain.
#define QK_SCALE 0.180336880f

#if __has_builtin(__builtin_amdgcn_exp2f)
__device__ __forceinline__ float exp2_fast(float x) { return __builtin_amdgcn_exp2f(x); }
#else
__device__ __forceinline__ float exp2_fast(float x) { return __expf(x * 0.69314718f); }
#endif

__device__ __forceinline__ u16 f2b(float x) {
  unsigned u = __builtin_bit_cast(unsigned, x);
  u += 0x7FFFu + ((u >> 16) & 1u);   // RNE
  return (u16)(u >> 16);
}

// pack two f32 -> two bf16 in one VALU op (word0 = lo, word1 = hi)
__device__ __forceinline__ u32 cvt_pk(float lo, float hi) {
  u32 r;
  asm("v_cvt_pk_bf16_f32 %0, %1, %2" : "=v"(r) : "v"(lo), "v"(hi));
  return r;
}

// ---------------- fp32 -> bf16 conversion (batched, vectorized) ----------------
__global__ __launch_bounds__(256) void cvt3_kernel(const float* __restrict__ s0,
                                                   const float* __restrict__ s1,
                                                   const float* __restrict__ s2,
                                                   u16* __restrict__ d0,
                                                   u16* __restrict__ d1,
                                                   u16* __restrict__ d2, int n4) {
  const int which = blockIdx.y;
  const float* src = which == 0 ? s0 : which == 1 ? s1 : s2;
  u16* dst = which == 0 ? d0 : which == 1 ? d1 : d2;
  int i = blockIdx.x * blockDim.x + threadIdx.x;
  int stride = gridDim.x * blockDim.x;
  for (; i < n4; i += stride) {
    float4 v = ((const float4*)src)[i];
    u16x4v o;
    o.x = f2b(v.x); o.y = f2b(v.y); o.z = f2b(v.z); o.w = f2b(v.w);
    ((u16x4v*)dst)[i] = o;
  }
}

__global__ __launch_bounds__(256) void cvt4_kernel(const float* __restrict__ s0,
                                                   const float* __restrict__ s1,
                                                   const float* __restrict__ s2,
                                                   const float* __restrict__ s3,
                                                   u16* __restrict__ d0,
                                                   u16* __restrict__ d1,
                                                   u16* __restrict__ d2,
                                                   u16* __restrict__ d3, int n4) {
  const int which = blockIdx.y;
  const float* src = which == 0 ? s0 : which == 1 ? s1 : which == 2 ? s2 : s3;
  u16* dst = which == 0 ? d0 : which == 1 ? d1 : which == 2 ? d2 : d3;
  const float sc = (which == 0) ? QK_SCALE : 1.0f;   // w_q pre-scaled
  int i = blockIdx.x * blockDim.x + threadIdx.x;
  int stride = gridDim.x * blockDim.x;
  for (; i < n4; i += stride) {
    float4 v = ((const float4*)src)[i];
    u16x4v o;
    o.x = f2b(v.x * sc); o.y = f2b(v.y * sc); o.z = f2b(v.z * sc); o.w = f2b(v.w * sc);
    ((u16x4v*)dst)[i] = o;
  }
}

// ---------------- shared GEMM body: C[4096, NT] = A * W^T + bias*bscale --------
// 128 x (NF*32) tile, BK=64, 4 waves (2x2), reg-prefetch next K-tile.
// MODE 0: bf16 -> [B,NH,T,HD]; MODE 1: fp32 rm; MODE 2: bf16 -> V^T [B,NH,HD,T].
template<int NF, int MODE>
__device__ __forceinline__ void gemm_body(const u16* __restrict__ A,
                                          const u16* __restrict__ W,
                                          const float* __restrict__ bias, float bscale,
                                          void* __restrict__ Cout,
                                          u16* lA, u16* lB) {
  const int tid = threadIdx.x;
  const int lane = tid & 63;
  const int wid = tid >> 6;
  const int wr = wid >> 1, wc = wid & 1;
  const int g = lane >> 4, fr = lane & 15;
  const int mt = blockIdx.y, nt = blockIdx.x;
  constexpr int NT = NF * 32;

  f32x4 acc[4][NF];
#pragma unroll
  for (int m = 0; m < 4; ++m)
#pragma unroll
    for (int n = 0; n < NF; ++n) acc[m][n] = (f32x4){0.f, 0.f, 0.f, 0.f};

  const int srow = tid >> 3;        // 0..31
  const int scol = (tid & 7) * 8;   // element col 0..56

  bf16x8 ra[4], rb[NF];
#pragma unroll
  for (int ps = 0; ps < 4; ++ps)
    ra[ps] = *(const bf16x8*)(A + (size_t)(mt * 128 + ps * 32 + srow) * Hh + scol);
#pragma unroll
  for (int ps = 0; ps < NF; ++ps)
    rb[ps] = *(const bf16x8*)(W + (size_t)(nt * NT + ps * 32 + srow) * Hh + scol);
#pragma unroll
  for (int ps = 0; ps < 4; ++ps) {
    int r = ps * 32 + srow;
    *(bf16x8*)((char*)lA + r * 128 + ((scol * 2) ^ ((r & 7) << 4))) = ra[ps];
  }
#pragma unroll
  for (int ps = 0; ps < NF; ++ps) {
    int r = ps * 32 + srow;
    *(bf16x8*)((char*)lB + r * 128 + ((scol * 2) ^ ((r & 7) << 4))) = rb[ps];
  }
  __syncthreads();

  for (int kt = 0; kt < Hh; kt += 64) {
    if (kt + 64 < Hh) {
#pragma unroll
      for (int ps = 0; ps < 4; ++ps)
        ra[ps] = *(const bf16x8*)(A + (size_t)(mt * 128 + ps * 32 + srow) * Hh + kt + 64 + scol);
#pragma unroll
      for (int ps = 0; ps < NF; ++ps)
        rb[ps] = *(const bf16x8*)(W + (size_t)(nt * NT + ps * 32 + srow) * Hh + kt + 64 + scol);
    }
    bf16x8 af[4][2], bfv[NF][2];
#pragma unroll
    for (int m = 0; m < 4; ++m)
#pragma unroll
      for (int ks = 0; ks < 2; ++ks) {
        int r = wr * 64 + m * 16 + fr;
        af[m][ks] = *(const bf16x8*)((const char*)lA + r * 128 + ((ks * 64 + g * 16) ^ ((r & 7) << 4)));
      }
#pragma unroll
    for (int n = 0; n < NF; ++n)
#pragma unroll
      for (int ks = 0; ks < 2; ++ks) {
        int r = wc * (NT / 2) + n * 16 + fr;
        bfv[n][ks] = *(const bf16x8*)((const char*)lB + r * 128 + ((ks * 64 + g * 16) ^ ((r & 7) << 4)));
      }
#pragma unroll
    for (int m = 0; m < 4; ++m)
#pragma unroll
      for (int n = 0; n < NF; ++n)
#pragma unroll
        for (int ks = 0; ks < 2; ++ks)
          acc[m][n] = __builtin_amdgcn_mfma_f32_16x16x32_bf16(af[m][ks], bfv[n][ks],
                                                              acc[m][n], 0, 0, 0);
    if (kt + 64 < Hh) {
      __syncthreads();
#pragma unroll
      for (int ps = 0; ps < 4; ++ps) {
        int r = ps * 32 + srow;
        *(bf16x8*)((char*)lA + r * 128 + ((scol * 2) ^ ((r & 7) << 4))) = ra[ps];
      }
#pragma unroll
      for (int ps = 0; ps < NF; ++ps) {
        int r = ps * 32 + srow;
        *(bf16x8*)((char*)lB + r * 128 + ((scol * 2) ^ ((r & 7) << 4))) = rb[ps];
      }
      __syncthreads();
    }
  }

#pragma unroll
  for (int n = 0; n < NF; ++n) {
    int Cc = nt * NT + wc * (NT / 2) + n * 16 + fr;
    float bv = bias[Cc] * bscale;
#pragma unroll
    for (int m = 0; m < 4; ++m) {
#pragma unroll
      for (int j = 0; j < 4; ++j) {
        int R = mt * 128 + wr * 64 + m * 16 + g * 4 + j;
        float val = acc[m][n][j] + bv;
        if constexpr (MODE == 0) {
          int bb = R >> 11, t = R & (Tt - 1);
          int h = Cc >> 6, d = Cc & 63;
          ((u16*)Cout)[(((size_t)(bb * NHh + h) * Tt + t) << 6) + d] = f2b(val);
        } else if constexpr (MODE == 2) {
          int bb = R >> 11, t = R & (Tt - 1);
          int h = Cc >> 6, d = Cc & 63;
          ((u16*)Cout)[(((size_t)(bb * NHh + h) * 64 + d) << 11) + t] = f2b(val);
        } else {
          ((float*)Cout)[(size_t)R * Hh + Cc] = val;
        }
      }
    }
  }
}

__global__ __launch_bounds__(256, 3) void proj_qkv_kernel(
    const u16* __restrict__ qb, const u16* __restrict__ kb, const u16* __restrict__ vb,
    const u16* __restrict__ wqb, const u16* __restrict__ wkb, const u16* __restrict__ wvb,
    const float* __restrict__ biq, const float* __restrict__ bik, const float* __restrict__ biv,
    u16* __restrict__ Qp, u16* __restrict__ Kp, u16* __restrict__ Vt) {
  __shared__ u16 lA[128 * 64];
  __shared__ u16 lB[64 * 64];
  const int z = blockIdx.z;
  const u16* A = (z == 0) ? qb : (z == 1) ? kb : vb;
  const u16* W = (z == 0) ? wqb : (z == 1) ? wkb : wvb;
  const float* bi = (z == 0) ? biq : (z == 1) ? bik : biv;
  if (z == 2) gemm_body<2, 2>(A, W, bi, 1.0f, Vt, lA, lB);
  else if (z == 0) gemm_body<2, 0>(A, W, bi, QK_SCALE, Qp, lA, lB);
  else gemm_body<2, 0>(A, W, bi, 1.0f, Kp, lA, lB);
}

__global__ __launch_bounds__(256, 2) void gemm_out_kernel(
    const u16* __restrict__ A, const u16* __restrict__ W,
    const float* __restrict__ bias, float* __restrict__ Cout) {
  __shared__ u16 lA[128 * 64];
  __shared__ u16 lB[64 * 64];
  gemm_body<2, 1>(A, W, bias, 1.0f, Cout, lA, lB);
}

// ---------------- flash attention (causal) ----------------
// QBLK=128 (4 waves x 32 q-rows as 2 halves), KVBLK=128 processed as two verified
// 64-kv subtiles per barrier: softmax once per 128 kv (half the shfl chains and
// barriers vs KVBLK=64), lP[128][64] reused across the two PV passes (wave-private
// rows, in-wave DS ordering). Swapped QK (mfma(K,Q)); exp2-domain softmax;
// P packed via v_cvt_pk_bf16_f32. Diagonal tile: waves 0-1 skip subtile B.
// 1-D grid of 512, remapped so co-resident block pairs have qt_a + qt_b = 15
// (uniform 17 kv-iters per CU). LDS 80KB -> 2 blocks/CU.
__global__ __launch_bounds__(256, 2) void attn_kernel(const u16* __restrict__ Qp,
                                                      const u16* __restrict__ Kp,
                                                      const u16* __restrict__ Vt,
                                                      u16* __restrict__ AO) {
  __shared__ u16 lK[2][128 * 64];      // [dbuf][kv=128][d=64], swz ^((row&7)<<4)
  __shared__ u16 lV[2][2][64 * 64];    // [dbuf][kvhalf][d=64][kv=64], same swz
  __shared__ u16 lP[128 * 64];
  const int tid = threadIdx.x;
  const int lane = tid & 63;
  const int w = tid >> 6;
  const int g = lane >> 4, fr = lane & 15;
  // balanced remap: CU-resident pair (L, L+256) gets qt and 15-qt
  const int L = blockIdx.x;
  const int idx = L & 255, half = L >> 8;
  const int bh = (half ? 16 : 0) + (idx >> 4);
  const int qt = half ? 15 - (idx & 15) : (idx & 15);
  const int q0 = qt * 128;

  bf16x8 qf[2][2];
#pragma unroll
  for (int h = 0; h < 2; ++h) {
    const u16* qrow = Qp + (((size_t)bh * Tt + q0 + w * 32 + h * 16 + fr) << 6) + g * 8;
    qf[h][0] = *(const bf16x8*)(qrow);
    qf[h][1] = *(const bf16x8*)(qrow + 32);
  }

  const int srow = tid >> 3;          // 0..31
  const int scol = (tid & 7) * 8;     // element col 0..56
  const int sswz = (scol * 2) ^ ((srow & 7) << 4);   // row&7 == srow&7 (offsets are x32)

  // prologue: tile 0 -> regs -> buf0
  bf16x8 rk[4], rv[4];
#pragma unroll
  for (int ps = 0; ps < 4; ++ps) {
    rk[ps] = *(const bf16x8*)(Kp + (((size_t)bh * Tt + ps * 32 + srow) << 6) + scol);
    rv[ps] = *(const bf16x8*)(Vt + (((size_t)bh * 64 + (ps & 1) * 32 + srow) << 11) +
                              (ps >> 1) * 64 + scol);
  }
#pragma unroll
  for (int ps = 0; ps < 4; ++ps) {
    *(bf16x8*)((char*)lK[0] + (ps * 32 + srow) * 128 + sswz) = rk[ps];
    *(bf16x8*)((char*)lV[0][ps >> 1] + ((ps & 1) * 32 + srow) * 128 + sswz) = rv[ps];
  }
  __syncthreads();

  float m_r[2] = {-1e30f, -1e30f}, l_r[2] = {0.f, 0.f};
  f32x4 acc[2][4];
#pragma unroll
  for (int h = 0; h < 2; ++h)
#pragma unroll
    for (int nd = 0; nd < 4; ++nd) acc[h][nd] = (f32x4){0.f, 0.f, 0.f, 0.f};

  for (int jt = 0; jt <= qt; ++jt) {
    const char* bK = (const char*)lK[jt & 1];
    const char* bV0 = (const char*)lV[jt & 1][0];
    const char* bV1 = (const char*)lV[jt & 1][1];
    // issue next tile's loads early (committed at iter end)
    if (jt < qt) {
#pragma unroll
      for (int ps = 0; ps < 4; ++ps) {
        rk[ps] = *(const bf16x8*)(Kp + (((size_t)bh * Tt + (jt + 1) * 128 + ps * 32 + srow) << 6) + scol);
        rv[ps] = *(const bf16x8*)(Vt + (((size_t)bh * 64 + (ps & 1) * 32 + srow) << 11) +
                                  (jt + 1) * 128 + (ps >> 1) * 64 + scol);
      }
    }
    const bool diag = (jt == qt);
    const bool skipB = diag && (w < 2);       // subtile B fully masked for waves 0,1
    const int NmaxC = skipB ? 4 : 8;          // frags computed
    const int Nmask0 = diag ? (w < 2 ? 0 : 4) : 8;   // first frag needing masking

    // QK^T swapped: s[h][N]: k = N*16 + g*4 + r, q = w*32 + h*16 + fr
    f32x4 s[2][8];
    __builtin_amdgcn_s_setprio(1);
#pragma unroll
    for (int N = 0; N < 8; ++N) {
      if (N < NmaxC) {
        s[0][N] = (f32x4){0.f, 0.f, 0.f, 0.f};
        s[1][N] = (f32x4){0.f, 0.f, 0.f, 0.f};
        int rbase = (N * 16 + fr) * 128;
        int rsw = (fr & 7) << 4;
#pragma unroll
        for (int ks = 0; ks < 2; ++ks) {
          bf16x8 ak = *(const bf16x8*)(bK + rbase + ((ks * 64 + g * 16) ^ rsw));
          s[0][N] = __builtin_amdgcn_mfma_f32_16x16x32_bf16(ak, qf[0][ks], s[0][N], 0, 0, 0);
          s[1][N] = __builtin_amdgcn_mfma_f32_16x16x32_bf16(ak, qf[1][ks], s[1][N], 0, 0, 0);
        }
      }
    }
    __builtin_amdgcn_s_setprio(0);

    // softmax over full 128-kv row (one pass: half the shfl chains of KVBLK=64)
    u32 pw[2][8][2];
#pragma unroll
    for (int h = 0; h < 2; ++h) {
      const int qoff = w * 32 + h * 16 + fr;
      float tm = -1e30f;
#pragma unroll
      for (int N = 0; N < 8; ++N) {
        if (N < NmaxC) {
          if (N >= Nmask0) {
#pragma unroll
            for (int r = 0; r < 4; ++r)
              if (N * 16 + g * 4 + r > qoff) s[h][N][r] = -1e30f;
          }
#pragma unroll
          for (int r = 0; r < 4; ++r) tm = fmaxf(tm, s[h][N][r]);
        }
      }
      tm = fmaxf(tm, __shfl_xor(tm, 16));
      tm = fmaxf(tm, __shfl_xor(tm, 32));
      // T13 defer-rescale
      if (!__all(tm <= m_r[h] + 8.0f)) {
        float mn = fmaxf(m_r[h], tm);
        float sc = exp2_fast(m_r[h] - mn);
        m_r[h] = mn;
        l_r[h] *= sc;
        float scj[4];
#pragma unroll
        for (int j = 0; j < 4; ++j) scj[j] = __shfl(sc, g * 4 + j);
#pragma unroll
        for (int nd = 0; nd < 4; ++nd)
#pragma unroll
          for (int j = 0; j < 4; ++j) acc[h][nd][j] *= scj[j];
      }
      float rs = 0.f;
#pragma unroll
      for (int N = 0; N < 8; ++N) {
        if (N < NmaxC) {
          float p0 = exp2_fast(s[h][N][0] - m_r[h]);
          float p1 = exp2_fast(s[h][N][1] - m_r[h]);
          float p2 = exp2_fast(s[h][N][2] - m_r[h]);
          float p3 = exp2_fast(s[h][N][3] - m_r[h]);
          rs += (p0 + p1) + (p2 + p3);
          pw[h][N][0] = cvt_pk(p0, p1);
          pw[h][N][1] = cvt_pk(p2, p3);
        }
      }
      rs += __shfl_xor(rs, 16);
      rs += __shfl_xor(rs, 32);
      l_r[h] += rs;
    }

    // PV in two subtile passes reusing lP (wave-private rows; in-wave DS ordering)
#pragma unroll
    for (int p = 0; p < 2; ++p) {
      if (p == 1 && skipB) break;
      bf16x8 pa[2][2];
#pragma unroll
      for (int h = 0; h < 2; ++h) {
        const int prow = w * 32 + h * 16 + fr;
        const int psw = (prow & 7) << 4;
        char* base = (char*)lP + prow * 128;
#pragma unroll
        for (int n = 0; n < 4; ++n)
          *(u32x2v*)(base + ((32 * n + 8 * g) ^ psw)) =
              (u32x2v){pw[h][p * 4 + n][0], pw[h][p * 4 + n][1]};
#pragma unroll
        for (int ks = 0; ks < 2; ++ks)
          pa[h][ks] = *(const bf16x8*)(base + ((ks * 64 + g * 16) ^ psw));
      }
      const char* bV = p ? bV1 : bV0;
      __builtin_amdgcn_s_setprio(1);
#pragma unroll
      for (int nd = 0; nd < 4; ++nd) {
        int rbase = (nd * 16 + fr) * 128;
        int rsw = (fr & 7) << 4;
#pragma unroll
        for (int ks = 0; ks < 2; ++ks) {
          bf16x8 bv = *(const bf16x8*)(bV + rbase + ((ks * 64 + g * 16) ^ rsw));
          acc[0][nd] = __builtin_amdgcn_mfma_f32_16x16x32_bf16(pa[0][ks], bv, acc[0][nd], 0, 0, 0);
          acc[1][nd] = __builtin_amdgcn_mfma_f32_16x16x32_bf16(pa[1][ks], bv, acc[1][nd], 0, 0, 0);
        }
      }
      __builtin_amdgcn_s_setprio(0);
    }

    // commit next tile to the other buffer; single barrier per 128 kv
    if (jt < qt) {
#pragma unroll
      for (int ps = 0; ps < 4; ++ps) {
        *(bf16x8*)((char*)lK[(jt + 1) & 1] + (ps * 32 + srow) * 128 + sswz) = rk[ps];
        *(bf16x8*)((char*)lV[(jt + 1) & 1][ps >> 1] + ((ps & 1) * 32 + srow) * 128 + sswz) = rv[ps];
      }
      __syncthreads();
    }
  }

  // epilogue: normalize, merge heads into AO [B,T,H] bf16
  const int b = bh >> 4, hh = bh & 15;
#pragma unroll
  for (int h = 0; h < 2; ++h) {
    float lj[4];
#pragma unroll
    for (int j = 0; j < 4; ++j) lj[j] = __shfl(l_r[h], g * 4 + j);
#pragma unroll
    for (int j = 0; j < 4; ++j) {
      float inv = 1.0f / lj[j];
      int qq = q0 + w * 32 + h * 16 + g * 4 + j;
      size_t base = (((size_t)b * Tt + qq) << 10) + hh * 64;
#pragma unroll
      for (int nd = 0; nd < 4; ++nd)
        AO[base + nd * 16 + fr] = f2b(acc[h][nd][j] * inv);
    }
  }
}

extern "C" void kernel_launch(void* const* d_in, const int* in_sizes, int n_in,
                              void* d_out, int out_size, void* d_ws, size_t ws_size,
                              hipStream_t stream) {
  const float* q   = (const float*)d_in[0];
  const float* k   = (const float*)d_in[1];
  const float* v   = (const float*)d_in[2];
  // d_in[3] = mask (known causal tril; unused)
  const float* wq  = (const float*)d_in[4];
  const float* bq  = (const float*)d_in[5];
  const float* wk  = (const float*)d_in[6];
  const float* bk  = (const float*)d_in[7];
  const float* wv  = (const float*)d_in[8];
  const float* bv  = (const float*)d_in[9];
  const float* wo  = (const float*)d_in[10];
  const float* bo  = (const float*)d_in[11];

  char* ws = (char*)d_ws;
  const size_t SZB = (size_t)Bb * Tt * Hh * 2;  // 8.39 MB
  const size_t WB  = (size_t)Hh * Hh * 2;       // 2.10 MB
  u16* qb  = (u16*)(ws);
  u16* kb  = (u16*)(ws + SZB);
  u16* vb  = (u16*)(ws + 2 * SZB);
  u16* wqb = (u16*)(ws + 3 * SZB);
  u16* wkb = (u16*)(ws + 3 * SZB + WB);
  u16* wvb = (u16*)(ws + 3 * SZB + 2 * WB);
  u16* wob = (u16*)(ws + 3 * SZB + 3 * WB);
  u16* Qp  = (u16*)(ws + 3 * SZB + 4 * WB);
  u16* Kp  = (u16*)(ws + 4 * SZB + 4 * WB);
  u16* Vt  = (u16*)(ws + 5 * SZB + 4 * WB);
  u16* AO  = qb;   // reuse (qb dead after projections)

  const int N4_IN = (Bb * Tt * Hh) / 4;
  const int N4_W  = (Hh * Hh) / 4;
  cvt3_kernel<<<dim3(512, 3), 256, 0, stream>>>(q, k, v, qb, kb, vb, N4_IN);
  cvt4_kernel<<<dim3(128, 4), 256, 0, stream>>>(wq, wk, wv, wo, wqb, wkb, wvb, wob, N4_W);

  proj_qkv_kernel<<<dim3(Hh / 64, (Bb * Tt) / 128, 3), 256, 0, stream>>>(
      qb, kb, vb, wqb, wkb, wvb, bq, bk, bv, Qp, Kp, Vt);

  attn_kernel<<<dim3(512), 256, 0, stream>>>(Qp, Kp, Vt, AO);

  gemm_out_kernel<<<dim3(Hh / 64, (Bb * Tt) / 128), 256, 0, stream>>>(
      AO, wob, bo, (float*)d_out);
}

// Round 9
// 121.236 us; speedup vs baseline: 1.0910x; 1.0910x over previous
//
#include <hip/hip_runtime.h>
#include <hip/hip_bf16.h>

// MHA: B=2 T=2048 H=1024 NH=16 HD=64. All matmuls via bf16 MFMA 16x16x32.
#define Bb 2
#define Tt 2048
#define Hh 1024
#define NHh 16

typedef short bf16x8 __attribute__((ext_vector_type(8)));
typedef float f32x4 __attribute__((ext_vector_type(4)));
typedef unsigned short u16;
typedef unsigned int u32;
typedef u16 u16x4v __attribute__((ext_vector_type(4)));
typedef u32 u32x2v __attribute__((ext_vector_type(2)));

// 0.125 * log2(e): folded into w_q/b_q so softmax runs in exp2 domain.
#define QK_SCALE 0.180336880f

#if __has_builtin(__builtin_amdgcn_exp2f)
__device__ __forceinline__ float exp2_fast(float x) { return __builtin_amdgcn_exp2f(x); }
#else
__device__ __forceinline__ float exp2_fast(float x) { return __expf(x * 0.69314718f); }
#endif

__device__ __forceinline__ u16 f2b(float x) {
  unsigned u = __builtin_bit_cast(unsigned, x);
  u += 0x7FFFu + ((u >> 16) & 1u);   // RNE
  return (u16)(u >> 16);
}

// pack two f32 -> two bf16 in one VALU op (word0 = lo, word1 = hi)
__device__ __forceinline__ u32 cvt_pk(float lo, float hi) {
  u32 r;
  asm("v_cvt_pk_bf16_f32 %0, %1, %2" : "=v"(r) : "v"(lo), "v"(hi));
  return r;
}

// ---------------- fp32 -> bf16 conversion (batched, vectorized) ----------------
__global__ __launch_bounds__(256) void cvt3_kernel(const float* __restrict__ s0,
                                                   const float* __restrict__ s1,
                                                   const float* __restrict__ s2,
                                                   u16* __restrict__ d0,
                                                   u16* __restrict__ d1,
                                                   u16* __restrict__ d2, int n4) {
  const int which = blockIdx.y;
  const float* src = which == 0 ? s0 : which == 1 ? s1 : s2;
  u16* dst = which == 0 ? d0 : which == 1 ? d1 : d2;
  int i = blockIdx.x * blockDim.x + threadIdx.x;
  int stride = gridDim.x * blockDim.x;
  for (; i < n4; i += stride) {
    float4 v = ((const float4*)src)[i];
    u16x4v o;
    o.x = f2b(v.x); o.y = f2b(v.y); o.z = f2b(v.z); o.w = f2b(v.w);
    ((u16x4v*)dst)[i] = o;
  }
}

__global__ __launch_bounds__(256) void cvt4_kernel(const float* __restrict__ s0,
                                                   const float* __restrict__ s1,
                                                   const float* __restrict__ s2,
                                                   const float* __restrict__ s3,
                                                   u16* __restrict__ d0,
                                                   u16* __restrict__ d1,
                                                   u16* __restrict__ d2,
                                                   u16* __restrict__ d3, int n4) {
  const int which = blockIdx.y;
  const float* src = which == 0 ? s0 : which == 1 ? s1 : which == 2 ? s2 : s3;
  u16* dst = which == 0 ? d0 : which == 1 ? d1 : which == 2 ? d2 : d3;
  const float sc = (which == 0) ? QK_SCALE : 1.0f;   // w_q pre-scaled
  int i = blockIdx.x * blockDim.x + threadIdx.x;
  int stride = gridDim.x * blockDim.x;
  for (; i < n4; i += stride) {
    float4 v = ((const float4*)src)[i];
    u16x4v o;
    o.x = f2b(v.x * sc); o.y = f2b(v.y * sc); o.z = f2b(v.z * sc); o.w = f2b(v.w * sc);
    ((u16x4v*)dst)[i] = o;
  }
}

// ---------------- shared GEMM body: C[4096, NT] = A * W^T + bias*bscale --------
// 128 x (NF*32) tile, BK=64, 4 waves (2x2), reg-prefetch next K-tile.
// MODE 0: bf16 -> [B,NH,T,HD]; MODE 1: fp32 rm; MODE 2: bf16 -> V^T [B,NH,HD,T].
template<int NF, int MODE>
__device__ __forceinline__ void gemm_body(const u16* __restrict__ A,
                                          const u16* __restrict__ W,
                                          const float* __restrict__ bias, float bscale,
                                          void* __restrict__ Cout,
                                          u16* lA, u16* lB) {
  const int tid = threadIdx.x;
  const int lane = tid & 63;
  const int wid = tid >> 6;
  const int wr = wid >> 1, wc = wid & 1;
  const int g = lane >> 4, fr = lane & 15;
  const int mt = blockIdx.y, nt = blockIdx.x;
  constexpr int NT = NF * 32;

  f32x4 acc[4][NF];
#pragma unroll
  for (int m = 0; m < 4; ++m)
#pragma unroll
    for (int n = 0; n < NF; ++n) acc[m][n] = (f32x4){0.f, 0.f, 0.f, 0.f};

  const int srow = tid >> 3;        // 0..31
  const int scol = (tid & 7) * 8;   // element col 0..56

  bf16x8 ra[4], rb[NF];
#pragma unroll
  for (int ps = 0; ps < 4; ++ps)
    ra[ps] = *(const bf16x8*)(A + (size_t)(mt * 128 + ps * 32 + srow) * Hh + scol);
#pragma unroll
  for (int ps = 0; ps < NF; ++ps)
    rb[ps] = *(const bf16x8*)(W + (size_t)(nt * NT + ps * 32 + srow) * Hh + scol);
#pragma unroll
  for (int ps = 0; ps < 4; ++ps) {
    int r = ps * 32 + srow;
    *(bf16x8*)((char*)lA + r * 128 + ((scol * 2) ^ ((r & 7) << 4))) = ra[ps];
  }
#pragma unroll
  for (int ps = 0; ps < NF; ++ps) {
    int r = ps * 32 + srow;
    *(bf16x8*)((char*)lB + r * 128 + ((scol * 2) ^ ((r & 7) << 4))) = rb[ps];
  }
  __syncthreads();

  for (int kt = 0; kt < Hh; kt += 64) {
    if (kt + 64 < Hh) {
#pragma unroll
      for (int ps = 0; ps < 4; ++ps)
        ra[ps] = *(const bf16x8*)(A + (size_t)(mt * 128 + ps * 32 + srow) * Hh + kt + 64 + scol);
#pragma unroll
      for (int ps = 0; ps < NF; ++ps)
        rb[ps] = *(const bf16x8*)(W + (size_t)(nt * NT + ps * 32 + srow) * Hh + kt + 64 + scol);
    }
    bf16x8 af[4][2], bfv[NF][2];
#pragma unroll
    for (int m = 0; m < 4; ++m)
#pragma unroll
      for (int ks = 0; ks < 2; ++ks) {
        int r = wr * 64 + m * 16 + fr;
        af[m][ks] = *(const bf16x8*)((const char*)lA + r * 128 + ((ks * 64 + g * 16) ^ ((r & 7) << 4)));
      }
#pragma unroll
    for (int n = 0; n < NF; ++n)
#pragma unroll
      for (int ks = 0; ks < 2; ++ks) {
        int r = wc * (NT / 2) + n * 16 + fr;
        bfv[n][ks] = *(const bf16x8*)((const char*)lB + r * 128 + ((ks * 64 + g * 16) ^ ((r & 7) << 4)));
      }
#pragma unroll
    for (int m = 0; m < 4; ++m)
#pragma unroll
      for (int n = 0; n < NF; ++n)
#pragma unroll
        for (int ks = 0; ks < 2; ++ks)
          acc[m][n] = __builtin_amdgcn_mfma_f32_16x16x32_bf16(af[m][ks], bfv[n][ks],
                                                              acc[m][n], 0, 0, 0);
    if (kt + 64 < Hh) {
      __syncthreads();
#pragma unroll
      for (int ps = 0; ps < 4; ++ps) {
        int r = ps * 32 + srow;
        *(bf16x8*)((char*)lA + r * 128 + ((scol * 2) ^ ((r & 7) << 4))) = ra[ps];
      }
#pragma unroll
      for (int ps = 0; ps < NF; ++ps) {
        int r = ps * 32 + srow;
        *(bf16x8*)((char*)lB + r * 128 + ((scol * 2) ^ ((r & 7) << 4))) = rb[ps];
      }
      __syncthreads();
    }
  }

#pragma unroll
  for (int n = 0; n < NF; ++n) {
    int Cc = nt * NT + wc * (NT / 2) + n * 16 + fr;
    float bv = bias[Cc] * bscale;
#pragma unroll
    for (int m = 0; m < 4; ++m) {
#pragma unroll
      for (int j = 0; j < 4; ++j) {
        int R = mt * 128 + wr * 64 + m * 16 + g * 4 + j;
        float val = acc[m][n][j] + bv;
        if constexpr (MODE == 0) {
          int bb = R >> 11, t = R & (Tt - 1);
          int h = Cc >> 6, d = Cc & 63;
          ((u16*)Cout)[(((size_t)(bb * NHh + h) * Tt + t) << 6) + d] = f2b(val);
        } else if constexpr (MODE == 2) {
          int bb = R >> 11, t = R & (Tt - 1);
          int h = Cc >> 6, d = Cc & 63;
          ((u16*)Cout)[(((size_t)(bb * NHh + h) * 64 + d) << 11) + t] = f2b(val);
        } else {
          ((float*)Cout)[(size_t)R * Hh + Cc] = val;
        }
      }
    }
  }
}

__global__ __launch_bounds__(256, 3) void proj_qkv_kernel(
    const u16* __restrict__ qb, const u16* __restrict__ kb, const u16* __restrict__ vb,
    const u16* __restrict__ wqb, const u16* __restrict__ wkb, const u16* __restrict__ wvb,
    const float* __restrict__ biq, const float* __restrict__ bik, const float* __restrict__ biv,
    u16* __restrict__ Qp, u16* __restrict__ Kp, u16* __restrict__ Vt) {
  __shared__ u16 lA[128 * 64];
  __shared__ u16 lB[64 * 64];
  const int z = blockIdx.z;
  const u16* A = (z == 0) ? qb : (z == 1) ? kb : vb;
  const u16* W = (z == 0) ? wqb : (z == 1) ? wkb : wvb;
  const float* bi = (z == 0) ? biq : (z == 1) ? bik : biv;
  if (z == 2) gemm_body<2, 2>(A, W, bi, 1.0f, Vt, lA, lB);
  else if (z == 0) gemm_body<2, 0>(A, W, bi, QK_SCALE, Qp, lA, lB);
  else gemm_body<2, 0>(A, W, bi, 1.0f, Kp, lA, lB);
}

__global__ __launch_bounds__(256, 2) void gemm_out_kernel(
    const u16* __restrict__ A, const u16* __restrict__ W,
    const float* __restrict__ bias, float* __restrict__ Cout) {
  __shared__ u16 lA[128 * 64];
  __shared__ u16 lB[64 * 64];
  gemm_body<2, 1>(A, W, bias, 1.0f, Cout, lA, lB);
}

// ---------------- flash attention (causal) ----------------
// QBLK=64 (4 waves x 16 q-rows), KVBLK=64, dbuf K/V LDS, 1 barrier/iter.
// Grid 1024 -> 4 blocks/CU (LDS 40KB each, 160KB total) = 4 waves/SIMD: doubles
// the TLP vs the 512-grid QBLK=128 version (which was latency-chain-bound at
// 2 waves/SIMD). Co-resident quadruple (L, L+256k) gets qt values with
// sum(qt+1) = 66 for every CU (uniform work).
// Swapped QK (mfma(K,Q)) -> full q-row in-lane; exp2-domain softmax;
// P packed via v_cvt_pk_bf16_f32; T13 defer-rescale; setprio on MFMA clusters.
__global__ __launch_bounds__(256, 4) void attn_kernel(const u16* __restrict__ Qp,
                                                      const u16* __restrict__ Kp,
                                                      const u16* __restrict__ Vt,
                                                      u16* __restrict__ AO) {
  __shared__ u16 lK[2][64 * 64];   // [dbuf][kv][d], swz ^((row&7)<<4)
  __shared__ u16 lV[2][64 * 64];   // [dbuf][d][kv], same swz
  __shared__ u16 lP[64 * 64];
  const int tid = threadIdx.x;
  const int lane = tid & 63;
  const int w = tid >> 6;
  const int g = lane >> 4, fr = lane & 15;
  // balanced remap: co-resident {k=0..3} get qt = {2s, 31-2s, 2s+1, 30-2s}
  const int L = blockIdx.x;
  const int i = L & 255, k4 = L >> 8;
  const int bh = i & 31, s8 = i >> 5;
  const int t2 = s8 * 2 + (k4 >> 1);
  const int qt = (k4 & 1) ? (31 - t2) : t2;
  const int q0 = qt * 64;

  // Q B-frag: q = q0 + w*16 + fr, d = ks*32 + g*8 + 0..7
  bf16x8 qf[2];
  {
    const u16* qrow = Qp + (((size_t)bh * Tt + q0 + w * 16 + fr) << 6) + g * 8;
    qf[0] = *(const bf16x8*)(qrow);
    qf[1] = *(const bf16x8*)(qrow + 32);
  }

  const int srow = tid >> 3;          // 0..31
  const int scol = (tid & 7) * 8;     // element col 0..56
  const int sswz = (scol * 2) ^ ((srow & 7) << 4);

  // prologue: tile 0 -> regs -> buf0
  bf16x8 rk[2], rv[2];
#pragma unroll
  for (int ps = 0; ps < 2; ++ps) {
    rk[ps] = *(const bf16x8*)(Kp + (((size_t)bh * Tt + ps * 32 + srow) << 6) + scol);
    rv[ps] = *(const bf16x8*)(Vt + (((size_t)bh * 64 + ps * 32 + srow) << 11) + scol);
  }
#pragma unroll
  for (int ps = 0; ps < 2; ++ps) {
    *(bf16x8*)((char*)lK[0] + (ps * 32 + srow) * 128 + sswz) = rk[ps];
    *(bf16x8*)((char*)lV[0] + (ps * 32 + srow) * 128 + sswz) = rv[ps];
  }
  __syncthreads();

  float m_r = -1e30f, l_r = 0.f;
  f32x4 acc[4];
#pragma unroll
  for (int nd = 0; nd < 4; ++nd) acc[nd] = (f32x4){0.f, 0.f, 0.f, 0.f};

  const int prow = w * 16 + fr;       // wave-private P row
  const int psw = (prow & 7) << 4;
  const int qoff = w * 16 + fr;       // q position within tile

  for (int jt = 0; jt <= qt; ++jt) {
    const char* bK = (const char*)lK[jt & 1];
    const char* bV = (const char*)lV[jt & 1];
    // issue next tile's loads early (committed at iter end)
    if (jt < qt) {
#pragma unroll
      for (int ps = 0; ps < 2; ++ps) {
        rk[ps] = *(const bf16x8*)(Kp + (((size_t)bh * Tt + (jt + 1) * 64 + ps * 32 + srow) << 6) + scol);
        rv[ps] = *(const bf16x8*)(Vt + (((size_t)bh * 64 + ps * 32 + srow) << 11) + (jt + 1) * 64 + scol);
      }
    }
    // QK^T swapped: s[n]: k = n*16 + g*4 + r, q = qoff
    f32x4 s[4];
    __builtin_amdgcn_s_setprio(1);
#pragma unroll
    for (int n = 0; n < 4; ++n) {
      s[n] = (f32x4){0.f, 0.f, 0.f, 0.f};
      int rbase = (n * 16 + fr) * 128;
      int rsw = (fr & 7) << 4;
#pragma unroll
      for (int ks = 0; ks < 2; ++ks) {
        bf16x8 ak = *(const bf16x8*)(bK + rbase + ((ks * 64 + g * 16) ^ rsw));
        s[n] = __builtin_amdgcn_mfma_f32_16x16x32_bf16(ak, qf[ks], s[n], 0, 0, 0);
      }
    }
    __builtin_amdgcn_s_setprio(0);

    // mask (diagonal tile only) + row max
    float tm = -1e30f;
    if (jt == qt) {
#pragma unroll
      for (int n = 0; n < 4; ++n)
#pragma unroll
        for (int r = 0; r < 4; ++r) {
          if (n * 16 + g * 4 + r > qoff) s[n][r] = -1e30f;
          tm = fmaxf(tm, s[n][r]);
        }
    } else {
#pragma unroll
      for (int n = 0; n < 4; ++n)
#pragma unroll
        for (int r = 0; r < 4; ++r) tm = fmaxf(tm, s[n][r]);
    }
    tm = fmaxf(tm, __shfl_xor(tm, 16));
    tm = fmaxf(tm, __shfl_xor(tm, 32));
    // T13 defer-rescale
    if (!__all(tm <= m_r + 8.0f)) {
      float mn = fmaxf(m_r, tm);
      float sc = exp2_fast(m_r - mn);
      m_r = mn;
      l_r *= sc;
      float scj[4];
#pragma unroll
      for (int j = 0; j < 4; ++j) scj[j] = __shfl(sc, g * 4 + j);
#pragma unroll
      for (int nd = 0; nd < 4; ++nd)
#pragma unroll
        for (int j = 0; j < 4; ++j) acc[nd][j] *= scj[j];
    }
    // exp2 + sum + pack
    float rs = 0.f;
    u32 pw[4][2];
#pragma unroll
    for (int n = 0; n < 4; ++n) {
      float p0 = exp2_fast(s[n][0] - m_r);
      float p1 = exp2_fast(s[n][1] - m_r);
      float p2 = exp2_fast(s[n][2] - m_r);
      float p3 = exp2_fast(s[n][3] - m_r);
      rs += (p0 + p1) + (p2 + p3);
      pw[n][0] = cvt_pk(p0, p1);
      pw[n][1] = cvt_pk(p2, p3);
    }
    rs += __shfl_xor(rs, 16);
    rs += __shfl_xor(rs, 32);
    l_r += rs;
    // write P row (wave-private, in-wave DS ordering) + read PV A-frags
    bf16x8 pa[2];
    {
      char* base = (char*)lP + prow * 128;
#pragma unroll
      for (int n = 0; n < 4; ++n)
        *(u32x2v*)(base + ((32 * n + 8 * g) ^ psw)) = (u32x2v){pw[n][0], pw[n][1]};
#pragma unroll
      for (int ks = 0; ks < 2; ++ks)
        pa[ks] = *(const bf16x8*)(base + ((ks * 64 + g * 16) ^ psw));
    }
    // PV: acc[nd] += P x V^T rows
    __builtin_amdgcn_s_setprio(1);
#pragma unroll
    for (int nd = 0; nd < 4; ++nd) {
      int rbase = (nd * 16 + fr) * 128;
      int rsw = (fr & 7) << 4;
#pragma unroll
      for (int ks = 0; ks < 2; ++ks) {
        bf16x8 bv = *(const bf16x8*)(bV + rbase + ((ks * 64 + g * 16) ^ rsw));
        acc[nd] = __builtin_amdgcn_mfma_f32_16x16x32_bf16(pa[ks], bv, acc[nd], 0, 0, 0);
      }
    }
    __builtin_amdgcn_s_setprio(0);
    // commit next tile to the other buffer; single barrier per iter
    if (jt < qt) {
#pragma unroll
      for (int ps = 0; ps < 2; ++ps) {
        *(bf16x8*)((char*)lK[(jt + 1) & 1] + (ps * 32 + srow) * 128 + sswz) = rk[ps];
        *(bf16x8*)((char*)lV[(jt + 1) & 1] + (ps * 32 + srow) * 128 + sswz) = rv[ps];
      }
      __syncthreads();
    }
  }

  // epilogue: normalize, merge heads into AO [B,T,H] bf16
  const int b = bh >> 4, hh = bh & 15;
  float lj[4];
#pragma unroll
  for (int j = 0; j < 4; ++j) lj[j] = __shfl(l_r, g * 4 + j);
#pragma unroll
  for (int j = 0; j < 4; ++j) {
    float inv = 1.0f / lj[j];
    int qq = q0 + w * 16 + g * 4 + j;
    size_t base = (((size_t)b * Tt + qq) << 10) + hh * 64;
#pragma unroll
    for (int nd = 0; nd < 4; ++nd)
      AO[base + nd * 16 + fr] = f2b(acc[nd][j] * inv);
  }
}

extern "C" void kernel_launch(void* const* d_in, const int* in_sizes, int n_in,
                              void* d_out, int out_size, void* d_ws, size_t ws_size,
                              hipStream_t stream) {
  const float* q   = (const float*)d_in[0];
  const float* k   = (const float*)d_in[1];
  const float* v   = (const float*)d_in[2];
  // d_in[3] = mask (known causal tril; unused)
  const float* wq  = (const float*)d_in[4];
  const float* bq  = (const float*)d_in[5];
  const float* wk  = (const float*)d_in[6];
  const float* bk  = (const float*)d_in[7];
  const float* wv  = (const float*)d_in[8];
  const float* bv  = (const float*)d_in[9];
  const float* wo  = (const float*)d_in[10];
  const float* bo  = (const float*)d_in[11];

  char* ws = (char*)d_ws;
  const size_t SZB = (size_t)Bb * Tt * Hh * 2;  // 8.39 MB
  const size_t WB  = (size_t)Hh * Hh * 2;       // 2.10 MB
  u16* qb  = (u16*)(ws);
  u16* kb  = (u16*)(ws + SZB);
  u16* vb  = (u16*)(ws + 2 * SZB);
  u16* wqb = (u16*)(ws + 3 * SZB);
  u16* wkb = (u16*)(ws + 3 * SZB + WB);
  u16* wvb = (u16*)(ws + 3 * SZB + 2 * WB);
  u16* wob = (u16*)(ws + 3 * SZB + 3 * WB);
  u16* Qp  = (u16*)(ws + 3 * SZB + 4 * WB);
  u16* Kp  = (u16*)(ws + 4 * SZB + 4 * WB);
  u16* Vt  = (u16*)(ws + 5 * SZB + 4 * WB);
  u16* AO  = qb;   // reuse (qb dead after projections)

  const int N4_IN = (Bb * Tt * Hh) / 4;
  const int N4_W  = (Hh * Hh) / 4;
  cvt3_kernel<<<dim3(512, 3), 256, 0, stream>>>(q, k, v, qb, kb, vb, N4_IN);
  cvt4_kernel<<<dim3(128, 4), 256, 0, stream>>>(wq, wk, wv, wo, wqb, wkb, wvb, wob, N4_W);

  proj_qkv_kernel<<<dim3(Hh / 64, (Bb * Tt) / 128, 3), 256, 0, stream>>>(
      qb, kb, vb, wqb, wkb, wvb, bq, bk, bv, Qp, Kp, Vt);

  attn_kernel<<<dim3(1024), 256, 0, stream>>>(Qp, Kp, Vt, AO);

  gemm_out_kernel<<<dim3(Hh / 64, (Bb * Tt) / 128), 256, 0, stream>>>(
      AO, wob, bo, (float*)d_out);
}

// Round 10
// 118.825 us; speedup vs baseline: 1.1131x; 1.0203x over previous
//
#include <hip/hip_runtime.h>
#include <hip/hip_bf16.h>

// MHA: B=2 T=2048 H=1024 NH=16 HD=64. All matmuls via bf16 MFMA 16x16x32.
#define Bb 2
#define Tt 2048
#define Hh 1024
#define NHh 16

typedef short bf16x8 __attribute__((ext_vector_type(8)));
typedef float f32x4 __attribute__((ext_vector_type(4)));
typedef unsigned short u16;
typedef unsigned int u32;
typedef u16 u16x4v __attribute__((ext_vector_type(4)));
typedef u32 u32x2v __attribute__((ext_vector_type(2)));

// 0.125 * log2(e): folded into w_q/b_q so softmax runs in exp2 domain.
#define QK_SCALE 0.180336880f

#if __has_builtin(__builtin_amdgcn_exp2f)
__device__ __forceinline__ float exp2_fast(float x) { return __builtin_amdgcn_exp2f(x); }
#else
__device__ __forceinline__ float exp2_fast(float x) { return __expf(x * 0.69314718f); }
#endif

__device__ __forceinline__ u16 f2b(float x) {
  unsigned u = __builtin_bit_cast(unsigned, x);
  u += 0x7FFFu + ((u >> 16) & 1u);   // RNE
  return (u16)(u >> 16);
}

// pack two f32 -> two bf16 in one VALU op (word0 = lo, word1 = hi)
__device__ __forceinline__ u32 cvt_pk(float lo, float hi) {
  u32 r;
  asm("v_cvt_pk_bf16_f32 %0, %1, %2" : "=v"(r) : "v"(lo), "v"(hi));
  return r;
}

// ---------------- fp32 -> bf16 weight conversion (batched, vectorized) ----------------
__global__ __launch_bounds__(256) void cvt4_kernel(const float* __restrict__ s0,
                                                   const float* __restrict__ s1,
                                                   const float* __restrict__ s2,
                                                   const float* __restrict__ s3,
                                                   u16* __restrict__ d0,
                                                   u16* __restrict__ d1,
                                                   u16* __restrict__ d2,
                                                   u16* __restrict__ d3, int n4) {
  const int which = blockIdx.y;
  const float* src = which == 0 ? s0 : which == 1 ? s1 : which == 2 ? s2 : s3;
  u16* dst = which == 0 ? d0 : which == 1 ? d1 : which == 2 ? d2 : d3;
  const float sc = (which == 0) ? QK_SCALE : 1.0f;   // w_q pre-scaled
  int i = blockIdx.x * blockDim.x + threadIdx.x;
  int stride = gridDim.x * blockDim.x;
  for (; i < n4; i += stride) {
    float4 v = ((const float4*)src)[i];
    u16x4v o;
    o.x = f2b(v.x * sc); o.y = f2b(v.y * sc); o.z = f2b(v.z * sc); o.w = f2b(v.w * sc);
    ((u16x4v*)dst)[i] = o;
  }
}

// ---------------- shared GEMM body: C[4096, NT] = A * W^T + bias*bscale --------
// 128 x (NF*32) tile, BK=64, 4 waves (2x2), reg-prefetch next K-tile.
// CVTA: A is fp32, converted to bf16 during staging (fuses the cvt kernel).
// MODE 0: bf16 -> [B,NH,T,HD]; MODE 1: fp32 rm; MODE 2: bf16 -> V^T [B,NH,HD,T].
template<int NF, int MODE, bool CVTA>
__device__ __forceinline__ void gemm_body(const void* __restrict__ Av,
                                          const u16* __restrict__ W,
                                          const float* __restrict__ bias, float bscale,
                                          void* __restrict__ Cout,
                                          u16* lA, u16* lB, int mt, int nt) {
  const int tid = threadIdx.x;
  const int lane = tid & 63;
  const int wid = tid >> 6;
  const int wr = wid >> 1, wc = wid & 1;
  const int g = lane >> 4, fr = lane & 15;
  constexpr int NT = NF * 32;

  f32x4 acc[4][NF];
#pragma unroll
  for (int m = 0; m < 4; ++m)
#pragma unroll
    for (int n = 0; n < NF; ++n) acc[m][n] = (f32x4){0.f, 0.f, 0.f, 0.f};

  const int srow = tid >> 3;        // 0..31
  const int scol = (tid & 7) * 8;   // element col 0..56

  bf16x8 ra[4], rb[NF];
#pragma unroll
  for (int ps = 0; ps < 4; ++ps) {
    size_t off = (size_t)(mt * 128 + ps * 32 + srow) * Hh + scol;
    if constexpr (CVTA) {
      float4 f0 = *(const float4*)((const float*)Av + off);
      float4 f1 = *(const float4*)((const float*)Av + off + 4);
      bf16x8 o;
      o[0] = (short)f2b(f0.x); o[1] = (short)f2b(f0.y);
      o[2] = (short)f2b(f0.z); o[3] = (short)f2b(f0.w);
      o[4] = (short)f2b(f1.x); o[5] = (short)f2b(f1.y);
      o[6] = (short)f2b(f1.z); o[7] = (short)f2b(f1.w);
      ra[ps] = o;
    } else {
      ra[ps] = *(const bf16x8*)((const u16*)Av + off);
    }
  }
#pragma unroll
  for (int ps = 0; ps < NF; ++ps)
    rb[ps] = *(const bf16x8*)(W + (size_t)(nt * NT + ps * 32 + srow) * Hh + scol);
#pragma unroll
  for (int ps = 0; ps < 4; ++ps) {
    int r = ps * 32 + srow;
    *(bf16x8*)((char*)lA + r * 128 + ((scol * 2) ^ ((r & 7) << 4))) = ra[ps];
  }
#pragma unroll
  for (int ps = 0; ps < NF; ++ps) {
    int r = ps * 32 + srow;
    *(bf16x8*)((char*)lB + r * 128 + ((scol * 2) ^ ((r & 7) << 4))) = rb[ps];
  }
  __syncthreads();

  for (int kt = 0; kt < Hh; kt += 64) {
    if (kt + 64 < Hh) {
#pragma unroll
      for (int ps = 0; ps < 4; ++ps) {
        size_t off = (size_t)(mt * 128 + ps * 32 + srow) * Hh + kt + 64 + scol;
        if constexpr (CVTA) {
          float4 f0 = *(const float4*)((const float*)Av + off);
          float4 f1 = *(const float4*)((const float*)Av + off + 4);
          bf16x8 o;
          o[0] = (short)f2b(f0.x); o[1] = (short)f2b(f0.y);
          o[2] = (short)f2b(f0.z); o[3] = (short)f2b(f0.w);
          o[4] = (short)f2b(f1.x); o[5] = (short)f2b(f1.y);
          o[6] = (short)f2b(f1.z); o[7] = (short)f2b(f1.w);
          ra[ps] = o;
        } else {
          ra[ps] = *(const bf16x8*)((const u16*)Av + off);
        }
      }
#pragma unroll
      for (int ps = 0; ps < NF; ++ps)
        rb[ps] = *(const bf16x8*)(W + (size_t)(nt * NT + ps * 32 + srow) * Hh + kt + 64 + scol);
    }
    bf16x8 af[4][2], bfv[NF][2];
#pragma unroll
    for (int m = 0; m < 4; ++m)
#pragma unroll
      for (int ks = 0; ks < 2; ++ks) {
        int r = wr * 64 + m * 16 + fr;
        af[m][ks] = *(const bf16x8*)((const char*)lA + r * 128 + ((ks * 64 + g * 16) ^ ((r & 7) << 4)));
      }
#pragma unroll
    for (int n = 0; n < NF; ++n)
#pragma unroll
      for (int ks = 0; ks < 2; ++ks) {
        int r = wc * (NT / 2) + n * 16 + fr;
        bfv[n][ks] = *(const bf16x8*)((const char*)lB + r * 128 + ((ks * 64 + g * 16) ^ ((r & 7) << 4)));
      }
#pragma unroll
    for (int m = 0; m < 4; ++m)
#pragma unroll
      for (int n = 0; n < NF; ++n)
#pragma unroll
        for (int ks = 0; ks < 2; ++ks)
          acc[m][n] = __builtin_amdgcn_mfma_f32_16x16x32_bf16(af[m][ks], bfv[n][ks],
                                                              acc[m][n], 0, 0, 0);
    if (kt + 64 < Hh) {
      __syncthreads();
#pragma unroll
      for (int ps = 0; ps < 4; ++ps) {
        int r = ps * 32 + srow;
        *(bf16x8*)((char*)lA + r * 128 + ((scol * 2) ^ ((r & 7) << 4))) = ra[ps];
      }
#pragma unroll
      for (int ps = 0; ps < NF; ++ps) {
        int r = ps * 32 + srow;
        *(bf16x8*)((char*)lB + r * 128 + ((scol * 2) ^ ((r & 7) << 4))) = rb[ps];
      }
      __syncthreads();
    }
  }

#pragma unroll
  for (int n = 0; n < NF; ++n) {
    int Cc = nt * NT + wc * (NT / 2) + n * 16 + fr;
    float bv = bias[Cc] * bscale;
#pragma unroll
    for (int m = 0; m < 4; ++m) {
#pragma unroll
      for (int j = 0; j < 4; ++j) {
        int R = mt * 128 + wr * 64 + m * 16 + g * 4 + j;
        float val = acc[m][n][j] + bv;
        if constexpr (MODE == 0) {
          int bb = R >> 11, t = R & (Tt - 1);
          int h = Cc >> 6, d = Cc & 63;
          ((u16*)Cout)[(((size_t)(bb * NHh + h) * Tt + t) << 6) + d] = f2b(val);
        } else if constexpr (MODE == 2) {
          int bb = R >> 11, t = R & (Tt - 1);
          int h = Cc >> 6, d = Cc & 63;
          ((u16*)Cout)[(((size_t)(bb * NHh + h) * 64 + d) << 11) + t] = f2b(val);
        } else {
          ((float*)Cout)[(size_t)R * Hh + Cc] = val;
        }
      }
    }
  }
}

// QKV projections, fused fp32->bf16 on the A path. 1-D grid of 1536 with
// XCD-aware remap: slot = (id&7) + 8*(j/16) colocates all 16 nt-blocks of one
// (z, mt) A-tile on ONE XCD, co-resident in the same dispatch round -> A-tile
// fetched once per XCD instead of 8x (FETCH_SIZE was 102 MB, 3.3x ideal).
__global__ __launch_bounds__(256, 3) void proj_qkv_kernel(
    const float* __restrict__ q, const float* __restrict__ k, const float* __restrict__ v,
    const u16* __restrict__ wqb, const u16* __restrict__ wkb, const u16* __restrict__ wvb,
    const float* __restrict__ biq, const float* __restrict__ bik, const float* __restrict__ biv,
    u16* __restrict__ Qp, u16* __restrict__ Kp, u16* __restrict__ Vt) {
  __shared__ u16 lA[128 * 64];
  __shared__ u16 lB[64 * 64];
  const int id = blockIdx.x;
  const int j = id >> 3;
  const int slot = (id & 7) + 8 * (j >> 4);   // 0..95 = (z, mt)
  const int nt = j & 15;
  const int z = slot >> 5, mt = slot & 31;
  if (z == 0)      gemm_body<2, 0, true>(q, wqb, biq, QK_SCALE, Qp, lA, lB, mt, nt);
  else if (z == 1) gemm_body<2, 0, true>(k, wkb, bik, 1.0f, Kp, lA, lB, mt, nt);
  else             gemm_body<2, 2, true>(v, wvb, biv, 1.0f, Vt, lA, lB, mt, nt);
}

// Output projection, XCD-remapped the same way (mt colocated per XCD).
__global__ __launch_bounds__(256, 2) void gemm_out_kernel(
    const u16* __restrict__ A, const u16* __restrict__ W,
    const float* __restrict__ bias, float* __restrict__ Cout) {
  __shared__ u16 lA[128 * 64];
  __shared__ u16 lB[64 * 64];
  const int id = blockIdx.x;
  const int j = id >> 3;
  const int mt = (id & 7) + 8 * (j >> 4);     // j>>4 in 0..3
  const int nt = j & 15;
  gemm_body<2, 1, false>(A, W, bias, 1.0f, Cout, lA, lB, mt, nt);
}

// ---------------- flash attention (causal) ----------------
// QBLK=64 (4 waves x 16 q-rows), KVBLK=64, dbuf K/V LDS, 1 barrier/iter.
// Grid 1024 -> 4 blocks/CU (LDS 40KB each) = 4 waves/SIMD. Co-resident
// quadruple gets qt values with uniform total work per CU.
__global__ __launch_bounds__(256, 4) void attn_kernel(const u16* __restrict__ Qp,
                                                      const u16* __restrict__ Kp,
                                                      const u16* __restrict__ Vt,
                                                      u16* __restrict__ AO) {
  __shared__ u16 lK[2][64 * 64];   // [dbuf][kv][d], swz ^((row&7)<<4)
  __shared__ u16 lV[2][64 * 64];   // [dbuf][d][kv], same swz
  __shared__ u16 lP[64 * 64];
  const int tid = threadIdx.x;
  const int lane = tid & 63;
  const int w = tid >> 6;
  const int g = lane >> 4, fr = lane & 15;
  // balanced remap: co-resident {k=0..3} get qt = {2s, 31-2s, 2s+1, 30-2s}
  const int L = blockIdx.x;
  const int i = L & 255, k4 = L >> 8;
  const int bh = i & 31, s8 = i >> 5;
  const int t2 = s8 * 2 + (k4 >> 1);
  const int qt = (k4 & 1) ? (31 - t2) : t2;
  const int q0 = qt * 64;

  // Q B-frag: q = q0 + w*16 + fr, d = ks*32 + g*8 + 0..7
  bf16x8 qf[2];
  {
    const u16* qrow = Qp + (((size_t)bh * Tt + q0 + w * 16 + fr) << 6) + g * 8;
    qf[0] = *(const bf16x8*)(qrow);
    qf[1] = *(const bf16x8*)(qrow + 32);
  }

  const int srow = tid >> 3;          // 0..31
  const int scol = (tid & 7) * 8;     // element col 0..56
  const int sswz = (scol * 2) ^ ((srow & 7) << 4);

  // prologue: tile 0 -> regs -> buf0
  bf16x8 rk[2], rv[2];
#pragma unroll
  for (int ps = 0; ps < 2; ++ps) {
    rk[ps] = *(const bf16x8*)(Kp + (((size_t)bh * Tt + ps * 32 + srow) << 6) + scol);
    rv[ps] = *(const bf16x8*)(Vt + (((size_t)bh * 64 + ps * 32 + srow) << 11) + scol);
  }
#pragma unroll
  for (int ps = 0; ps < 2; ++ps) {
    *(bf16x8*)((char*)lK[0] + (ps * 32 + srow) * 128 + sswz) = rk[ps];
    *(bf16x8*)((char*)lV[0] + (ps * 32 + srow) * 128 + sswz) = rv[ps];
  }
  __syncthreads();

  float m_r = -1e30f, l_r = 0.f;
  f32x4 acc[4];
#pragma unroll
  for (int nd = 0; nd < 4; ++nd) acc[nd] = (f32x4){0.f, 0.f, 0.f, 0.f};

  const int prow = w * 16 + fr;       // wave-private P row
  const int psw = (prow & 7) << 4;
  const int qoff = w * 16 + fr;       // q position within tile

  for (int jt = 0; jt <= qt; ++jt) {
    const char* bK = (const char*)lK[jt & 1];
    const char* bV = (const char*)lV[jt & 1];
    // issue next tile's loads early (committed at iter end)
    if (jt < qt) {
#pragma unroll
      for (int ps = 0; ps < 2; ++ps) {
        rk[ps] = *(const bf16x8*)(Kp + (((size_t)bh * Tt + (jt + 1) * 64 + ps * 32 + srow) << 6) + scol);
        rv[ps] = *(const bf16x8*)(Vt + (((size_t)bh * 64 + ps * 32 + srow) << 11) + (jt + 1) * 64 + scol);
      }
    }
    // QK^T swapped: s[n]: k = n*16 + g*4 + r, q = qoff
    f32x4 s[4];
    __builtin_amdgcn_s_setprio(1);
#pragma unroll
    for (int n = 0; n < 4; ++n) {
      s[n] = (f32x4){0.f, 0.f, 0.f, 0.f};
      int rbase = (n * 16 + fr) * 128;
      int rsw = (fr & 7) << 4;
#pragma unroll
      for (int ks = 0; ks < 2; ++ks) {
        bf16x8 ak = *(const bf16x8*)(bK + rbase + ((ks * 64 + g * 16) ^ rsw));
        s[n] = __builtin_amdgcn_mfma_f32_16x16x32_bf16(ak, qf[ks], s[n], 0, 0, 0);
      }
    }
    __builtin_amdgcn_s_setprio(0);

    // mask (diagonal tile only) + row max
    float tm = -1e30f;
    if (jt == qt) {
#pragma unroll
      for (int n = 0; n < 4; ++n)
#pragma unroll
        for (int r = 0; r < 4; ++r) {
          if (n * 16 + g * 4 + r > qoff) s[n][r] = -1e30f;
          tm = fmaxf(tm, s[n][r]);
        }
    } else {
#pragma unroll
      for (int n = 0; n < 4; ++n)
#pragma unroll
        for (int r = 0; r < 4; ++r) tm = fmaxf(tm, s[n][r]);
    }
    tm = fmaxf(tm, __shfl_xor(tm, 16));
    tm = fmaxf(tm, __shfl_xor(tm, 32));
    // T13 defer-rescale
    if (!__all(tm <= m_r + 8.0f)) {
      float mn = fmaxf(m_r, tm);
      float sc = exp2_fast(m_r - mn);
      m_r = mn;
      l_r *= sc;
      float scj[4];
#pragma unroll
      for (int j = 0; j < 4; ++j) scj[j] = __shfl(sc, g * 4 + j);
#pragma unroll
      for (int nd = 0; nd < 4; ++nd)
#pragma unroll
        for (int j = 0; j < 4; ++j) acc[nd][j] *= scj[j];
    }
    // exp2 + sum + pack
    float rs = 0.f;
    u32 pw[4][2];
#pragma unroll
    for (int n = 0; n < 4; ++n) {
      float p0 = exp2_fast(s[n][0] - m_r);
      float p1 = exp2_fast(s[n][1] - m_r);
      float p2 = exp2_fast(s[n][2] - m_r);
      float p3 = exp2_fast(s[n][3] - m_r);
      rs += (p0 + p1) + (p2 + p3);
      pw[n][0] = cvt_pk(p0, p1);
      pw[n][1] = cvt_pk(p2, p3);
    }
    rs += __shfl_xor(rs, 16);
    rs += __shfl_xor(rs, 32);
    l_r += rs;
    // write P row (wave-private, in-wave DS ordering) + read PV A-frags
    bf16x8 pa[2];
    {
      char* base = (char*)lP + prow * 128;
#pragma unroll
      for (int n = 0; n < 4; ++n)
        *(u32x2v*)(base + ((32 * n + 8 * g) ^ psw)) = (u32x2v){pw[n][0], pw[n][1]};
#pragma unroll
      for (int ks = 0; ks < 2; ++ks)
        pa[ks] = *(const bf16x8*)(base + ((ks * 64 + g * 16) ^ psw));
    }
    // PV: acc[nd] += P x V^T rows
    __builtin_amdgcn_s_setprio(1);
#pragma unroll
    for (int nd = 0; nd < 4; ++nd) {
      int rbase = (nd * 16 + fr) * 128;
      int rsw = (fr & 7) << 4;
#pragma unroll
      for (int ks = 0; ks < 2; ++ks) {
        bf16x8 bv = *(const bf16x8*)(bV + rbase + ((ks * 64 + g * 16) ^ rsw));
        acc[nd] = __builtin_amdgcn_mfma_f32_16x16x32_bf16(pa[ks], bv, acc[nd], 0, 0, 0);
      }
    }
    __builtin_amdgcn_s_setprio(0);
    // commit next tile to the other buffer; single barrier per iter
    if (jt < qt) {
#pragma unroll
      for (int ps = 0; ps < 2; ++ps) {
        *(bf16x8*)((char*)lK[(jt + 1) & 1] + (ps * 32 + srow) * 128 + sswz) = rk[ps];
        *(bf16x8*)((char*)lV[(jt + 1) & 1] + (ps * 32 + srow) * 128 + sswz) = rv[ps];
      }
      __syncthreads();
    }
  }

  // epilogue: normalize, merge heads into AO [B,T,H] bf16
  const int b = bh >> 4, hh = bh & 15;
  float lj[4];
#pragma unroll
  for (int j = 0; j < 4; ++j) lj[j] = __shfl(l_r, g * 4 + j);
#pragma unroll
  for (int j = 0; j < 4; ++j) {
    float inv = 1.0f / lj[j];
    int qq = q0 + w * 16 + g * 4 + j;
    size_t base = (((size_t)b * Tt + qq) << 10) + hh * 64;
#pragma unroll
    for (int nd = 0; nd < 4; ++nd)
      AO[base + nd * 16 + fr] = f2b(acc[nd][j] * inv);
  }
}

extern "C" void kernel_launch(void* const* d_in, const int* in_sizes, int n_in,
                              void* d_out, int out_size, void* d_ws, size_t ws_size,
                              hipStream_t stream) {
  const float* q   = (const float*)d_in[0];
  const float* k   = (const float*)d_in[1];
  const float* v   = (const float*)d_in[2];
  // d_in[3] = mask (known causal tril; unused)
  const float* wq  = (const float*)d_in[4];
  const float* bq  = (const float*)d_in[5];
  const float* wk  = (const float*)d_in[6];
  const float* bk  = (const float*)d_in[7];
  const float* wv  = (const float*)d_in[8];
  const float* bv  = (const float*)d_in[9];
  const float* wo  = (const float*)d_in[10];
  const float* bo  = (const float*)d_in[11];

  char* ws = (char*)d_ws;
  const size_t SZB = (size_t)Bb * Tt * Hh * 2;  // 8.39 MB
  const size_t WB  = (size_t)Hh * Hh * 2;       // 2.10 MB
  u16* wqb = (u16*)(ws);
  u16* wkb = (u16*)(ws + WB);
  u16* wvb = (u16*)(ws + 2 * WB);
  u16* wob = (u16*)(ws + 3 * WB);
  u16* Qp  = (u16*)(ws + 4 * WB);
  u16* Kp  = (u16*)(ws + 4 * WB + SZB);
  u16* Vt  = (u16*)(ws + 4 * WB + 2 * SZB);
  u16* AO  = (u16*)(ws + 4 * WB + 3 * SZB);

  const int N4_W = (Hh * Hh) / 4;
  cvt4_kernel<<<dim3(128, 4), 256, 0, stream>>>(wq, wk, wv, wo, wqb, wkb, wvb, wob, N4_W);

  proj_qkv_kernel<<<dim3(1536), 256, 0, stream>>>(
      q, k, v, wqb, wkb, wvb, bq, bk, bv, Qp, Kp, Vt);

  attn_kernel<<<dim3(1024), 256, 0, stream>>>(Qp, Kp, Vt, AO);

  gemm_out_kernel<<<dim3(512), 256, 0, stream>>>(
      AO, wob, bo, (float*)d_out);
}

// Round 11
// 114.441 us; speedup vs baseline: 1.1558x; 1.0383x over previous
//
#include <hip/hip_runtime.h>
#include <hip/hip_bf16.h>

// MHA: B=2 T=2048 H=1024 NH=16 HD=64. All matmuls via bf16 MFMA 16x16x32.
#define Bb 2
#define Tt 2048
#define Hh 1024
#define NHh 16

typedef short bf16x8 __attribute__((ext_vector_type(8)));
typedef float f32x4 __attribute__((ext_vector_type(4)));
typedef unsigned short u16;
typedef unsigned int u32;
typedef u16 u16x4v __attribute__((ext_vector_type(4)));
typedef u32 u32x2v __attribute__((ext_vector_type(2)));

// 0.125 * log2(e): folded into w_q/b_q so softmax runs in exp2 domain.
#define QK_SCALE 0.180336880f

#if __has_builtin(__builtin_amdgcn_exp2f)
__device__ __forceinline__ float exp2_fast(float x) { return __builtin_amdgcn_exp2f(x); }
#else
__device__ __forceinline__ float exp2_fast(float x) { return __expf(x * 0.69314718f); }
#endif

__device__ __forceinline__ u16 f2b(float x) {
  unsigned u = __builtin_bit_cast(unsigned, x);
  u += 0x7FFFu + ((u >> 16) & 1u);   // RNE
  return (u16)(u >> 16);
}

// pack two f32 -> two bf16 in one VALU op (word0 = lo, word1 = hi)
__device__ __forceinline__ u32 cvt_pk(float lo, float hi) {
  u32 r;
  asm("v_cvt_pk_bf16_f32 %0, %1, %2" : "=v"(r) : "v"(lo), "v"(hi));
  return r;
}

// ---------------- fp32 -> bf16 conversion (batched, vectorized) ----------------
__global__ __launch_bounds__(256) void cvt3_kernel(const float* __restrict__ s0,
                                                   const float* __restrict__ s1,
                                                   const float* __restrict__ s2,
                                                   u16* __restrict__ d0,
                                                   u16* __restrict__ d1,
                                                   u16* __restrict__ d2, int n4) {
  const int which = blockIdx.y;
  const float* src = which == 0 ? s0 : which == 1 ? s1 : s2;
  u16* dst = which == 0 ? d0 : which == 1 ? d1 : d2;
  int i = blockIdx.x * blockDim.x + threadIdx.x;
  int stride = gridDim.x * blockDim.x;
  for (; i < n4; i += stride) {
    float4 v = ((const float4*)src)[i];
    u16x4v o;
    o.x = f2b(v.x); o.y = f2b(v.y); o.z = f2b(v.z); o.w = f2b(v.w);
    ((u16x4v*)dst)[i] = o;
  }
}

__global__ __launch_bounds__(256) void cvt4_kernel(const float* __restrict__ s0,
                                                   const float* __restrict__ s1,
                                                   const float* __restrict__ s2,
                                                   const float* __restrict__ s3,
                                                   u16* __restrict__ d0,
                                                   u16* __restrict__ d1,
                                                   u16* __restrict__ d2,
                                                   u16* __restrict__ d3, int n4) {
  const int which = blockIdx.y;
  const float* src = which == 0 ? s0 : which == 1 ? s1 : which == 2 ? s2 : s3;
  u16* dst = which == 0 ? d0 : which == 1 ? d1 : which == 2 ? d2 : d3;
  const float sc = (which == 0) ? QK_SCALE : 1.0f;   // w_q pre-scaled
  int i = blockIdx.x * blockDim.x + threadIdx.x;
  int stride = gridDim.x * blockDim.x;
  for (; i < n4; i += stride) {
    float4 v = ((const float4*)src)[i];
    u16x4v o;
    o.x = f2b(v.x * sc); o.y = f2b(v.y * sc); o.z = f2b(v.z * sc); o.w = f2b(v.w * sc);
    ((u16x4v*)dst)[i] = o;
  }
}

// ---------------- shared GEMM body: C[4096, NT] = A * W^T + bias*bscale --------
// 128 x (NF*32) tile, BK=64, 4 waves (2x2), reg-prefetch next K-tile.
// MODE 0: bf16 -> [B,NH,T,HD]; MODE 1: fp32 rm; MODE 2: bf16 -> V^T [B,NH,HD,T].
template<int NF, int MODE>
__device__ __forceinline__ void gemm_body(const u16* __restrict__ A,
                                          const u16* __restrict__ W,
                                          const float* __restrict__ bias, float bscale,
                                          void* __restrict__ Cout,
                                          u16* lA, u16* lB, int mt, int nt) {
  const int tid = threadIdx.x;
  const int lane = tid & 63;
  const int wid = tid >> 6;
  const int wr = wid >> 1, wc = wid & 1;
  const int g = lane >> 4, fr = lane & 15;
  constexpr int NT = NF * 32;

  f32x4 acc[4][NF];
#pragma unroll
  for (int m = 0; m < 4; ++m)
#pragma unroll
    for (int n = 0; n < NF; ++n) acc[m][n] = (f32x4){0.f, 0.f, 0.f, 0.f};

  const int srow = tid >> 3;        // 0..31
  const int scol = (tid & 7) * 8;   // element col 0..56

  bf16x8 ra[4], rb[NF];
#pragma unroll
  for (int ps = 0; ps < 4; ++ps)
    ra[ps] = *(const bf16x8*)(A + (size_t)(mt * 128 + ps * 32 + srow) * Hh + scol);
#pragma unroll
  for (int ps = 0; ps < NF; ++ps)
    rb[ps] = *(const bf16x8*)(W + (size_t)(nt * NT + ps * 32 + srow) * Hh + scol);
#pragma unroll
  for (int ps = 0; ps < 4; ++ps) {
    int r = ps * 32 + srow;
    *(bf16x8*)((char*)lA + r * 128 + ((scol * 2) ^ ((r & 7) << 4))) = ra[ps];
  }
#pragma unroll
  for (int ps = 0; ps < NF; ++ps) {
    int r = ps * 32 + srow;
    *(bf16x8*)((char*)lB + r * 128 + ((scol * 2) ^ ((r & 7) << 4))) = rb[ps];
  }
  __syncthreads();

  for (int kt = 0; kt < Hh; kt += 64) {
    if (kt + 64 < Hh) {
#pragma unroll
      for (int ps = 0; ps < 4; ++ps)
        ra[ps] = *(const bf16x8*)(A + (size_t)(mt * 128 + ps * 32 + srow) * Hh + kt + 64 + scol);
#pragma unroll
      for (int ps = 0; ps < NF; ++ps)
        rb[ps] = *(const bf16x8*)(W + (size_t)(nt * NT + ps * 32 + srow) * Hh + kt + 64 + scol);
    }
    bf16x8 af[4][2], bfv[NF][2];
#pragma unroll
    for (int m = 0; m < 4; ++m)
#pragma unroll
      for (int ks = 0; ks < 2; ++ks) {
        int r = wr * 64 + m * 16 + fr;
        af[m][ks] = *(const bf16x8*)((const char*)lA + r * 128 + ((ks * 64 + g * 16) ^ ((r & 7) << 4)));
      }
#pragma unroll
    for (int n = 0; n < NF; ++n)
#pragma unroll
      for (int ks = 0; ks < 2; ++ks) {
        int r = wc * (NT / 2) + n * 16 + fr;
        bfv[n][ks] = *(const bf16x8*)((const char*)lB + r * 128 + ((ks * 64 + g * 16) ^ ((r & 7) << 4)));
      }
#pragma unroll
    for (int m = 0; m < 4; ++m)
#pragma unroll
      for (int n = 0; n < NF; ++n)
#pragma unroll
        for (int ks = 0; ks < 2; ++ks)
          acc[m][n] = __builtin_amdgcn_mfma_f32_16x16x32_bf16(af[m][ks], bfv[n][ks],
                                                              acc[m][n], 0, 0, 0);
    if (kt + 64 < Hh) {
      __syncthreads();
#pragma unroll
      for (int ps = 0; ps < 4; ++ps) {
        int r = ps * 32 + srow;
        *(bf16x8*)((char*)lA + r * 128 + ((scol * 2) ^ ((r & 7) << 4))) = ra[ps];
      }
#pragma unroll
      for (int ps = 0; ps < NF; ++ps) {
        int r = ps * 32 + srow;
        *(bf16x8*)((char*)lB + r * 128 + ((scol * 2) ^ ((r & 7) << 4))) = rb[ps];
      }
      __syncthreads();
    }
  }

#pragma unroll
  for (int n = 0; n < NF; ++n) {
    int Cc = nt * NT + wc * (NT / 2) + n * 16 + fr;
    float bv = bias[Cc] * bscale;
#pragma unroll
    for (int m = 0; m < 4; ++m) {
#pragma unroll
      for (int j = 0; j < 4; ++j) {
        int R = mt * 128 + wr * 64 + m * 16 + g * 4 + j;
        float val = acc[m][n][j] + bv;
        if constexpr (MODE == 0) {
          int bb = R >> 11, t = R & (Tt - 1);
          int h = Cc >> 6, d = Cc & 63;
          ((u16*)Cout)[(((size_t)(bb * NHh + h) * Tt + t) << 6) + d] = f2b(val);
        } else if constexpr (MODE == 2) {
          int bb = R >> 11, t = R & (Tt - 1);
          int h = Cc >> 6, d = Cc & 63;
          ((u16*)Cout)[(((size_t)(bb * NHh + h) * 64 + d) << 11) + t] = f2b(val);
        } else {
          ((float*)Cout)[(size_t)R * Hh + Cc] = val;
        }
      }
    }
  }
}

// QKV projections (bf16 A). 1-D grid of 1536 with XCD-aware remap:
// slot = (id&7) + 8*(j/16) colocates all 16 nt-blocks of one (z, mt) A-tile on
// ONE XCD, co-resident in the same dispatch round -> A-tile fetched once per
// XCD instead of 8x (verified: FETCH_SIZE 102 -> 57 MB in round 10).
__global__ __launch_bounds__(256, 3) void proj_qkv_kernel(
    const u16* __restrict__ qb, const u16* __restrict__ kb, const u16* __restrict__ vb,
    const u16* __restrict__ wqb, const u16* __restrict__ wkb, const u16* __restrict__ wvb,
    const float* __restrict__ biq, const float* __restrict__ bik, const float* __restrict__ biv,
    u16* __restrict__ Qp, u16* __restrict__ Kp, u16* __restrict__ Vt) {
  __shared__ u16 lA[128 * 64];
  __shared__ u16 lB[64 * 64];
  const int id = blockIdx.x;
  const int j = id >> 3;
  const int slot = (id & 7) + 8 * (j >> 4);   // 0..95 = (z, mt)
  const int nt = j & 15;
  const int z = slot >> 5, mt = slot & 31;
  if (z == 0)      gemm_body<2, 0>(qb, wqb, biq, QK_SCALE, Qp, lA, lB, mt, nt);
  else if (z == 1) gemm_body<2, 0>(kb, wkb, bik, 1.0f, Kp, lA, lB, mt, nt);
  else             gemm_body<2, 2>(vb, wvb, biv, 1.0f, Vt, lA, lB, mt, nt);
}

// Output projection, XCD-remapped the same way (mt colocated per XCD).
__global__ __launch_bounds__(256, 2) void gemm_out_kernel(
    const u16* __restrict__ A, const u16* __restrict__ W,
    const float* __restrict__ bias, float* __restrict__ Cout) {
  __shared__ u16 lA[128 * 64];
  __shared__ u16 lB[64 * 64];
  const int id = blockIdx.x;
  const int j = id >> 3;
  const int mt = (id & 7) + 8 * (j >> 4);     // j>>4 in 0..3
  const int nt = j & 15;
  gemm_body<2, 1>(A, W, bias, 1.0f, Cout, lA, lB, mt, nt);
}

// ---------------- flash attention (causal) ----------------
// QBLK=64 (4 waves x 16 q-rows), KVBLK=64, dbuf K/V LDS, 1 barrier/iter.
// Grid 1024 -> 4 blocks/CU (LDS 40KB each) = 4 waves/SIMD. Co-resident
// quadruple gets qt values with uniform total work per CU.
__global__ __launch_bounds__(256, 4) void attn_kernel(const u16* __restrict__ Qp,
                                                      const u16* __restrict__ Kp,
                                                      const u16* __restrict__ Vt,
                                                      u16* __restrict__ AO) {
  __shared__ u16 lK[2][64 * 64];   // [dbuf][kv][d], swz ^((row&7)<<4)
  __shared__ u16 lV[2][64 * 64];   // [dbuf][d][kv], same swz
  __shared__ u16 lP[64 * 64];
  const int tid = threadIdx.x;
  const int lane = tid & 63;
  const int w = tid >> 6;
  const int g = lane >> 4, fr = lane & 15;
  // balanced remap: co-resident {k=0..3} get qt = {2s, 31-2s, 2s+1, 30-2s}
  const int L = blockIdx.x;
  const int i = L & 255, k4 = L >> 8;
  const int bh = i & 31, s8 = i >> 5;
  const int t2 = s8 * 2 + (k4 >> 1);
  const int qt = (k4 & 1) ? (31 - t2) : t2;
  const int q0 = qt * 64;

  // Q B-frag: q = q0 + w*16 + fr, d = ks*32 + g*8 + 0..7
  bf16x8 qf[2];
  {
    const u16* qrow = Qp + (((size_t)bh * Tt + q0 + w * 16 + fr) << 6) + g * 8;
    qf[0] = *(const bf16x8*)(qrow);
    qf[1] = *(const bf16x8*)(qrow + 32);
  }

  const int srow = tid >> 3;          // 0..31
  const int scol = (tid & 7) * 8;     // element col 0..56
  const int sswz = (scol * 2) ^ ((srow & 7) << 4);

  // prologue: tile 0 -> regs -> buf0
  bf16x8 rk[2], rv[2];
#pragma unroll
  for (int ps = 0; ps < 2; ++ps) {
    rk[ps] = *(const bf16x8*)(Kp + (((size_t)bh * Tt + ps * 32 + srow) << 6) + scol);
    rv[ps] = *(const bf16x8*)(Vt + (((size_t)bh * 64 + ps * 32 + srow) << 11) + scol);
  }
#pragma unroll
  for (int ps = 0; ps < 2; ++ps) {
    *(bf16x8*)((char*)lK[0] + (ps * 32 + srow) * 128 + sswz) = rk[ps];
    *(bf16x8*)((char*)lV[0] + (ps * 32 + srow) * 128 + sswz) = rv[ps];
  }
  __syncthreads();

  float m_r = -1e30f, l_r = 0.f;
  f32x4 acc[4];
#pragma unroll
  for (int nd = 0; nd < 4; ++nd) acc[nd] = (f32x4){0.f, 0.f, 0.f, 0.f};

  const int prow = w * 16 + fr;       // wave-private P row
  const int psw = (prow & 7) << 4;
  const int qoff = w * 16 + fr;       // q position within tile

  for (int jt = 0; jt <= qt; ++jt) {
    const char* bK = (const char*)lK[jt & 1];
    const char* bV = (const char*)lV[jt & 1];
    // issue next tile's loads early (committed at iter end)
    if (jt < qt) {
#pragma unroll
      for (int ps = 0; ps < 2; ++ps) {
        rk[ps] = *(const bf16x8*)(Kp + (((size_t)bh * Tt + (jt + 1) * 64 + ps * 32 + srow) << 6) + scol);
        rv[ps] = *(const bf16x8*)(Vt + (((size_t)bh * 64 + ps * 32 + srow) << 11) + (jt + 1) * 64 + scol);
      }
    }
    // QK^T swapped: s[n]: k = n*16 + g*4 + r, q = qoff
    f32x4 s[4];
    __builtin_amdgcn_s_setprio(1);
#pragma unroll
    for (int n = 0; n < 4; ++n) {
      s[n] = (f32x4){0.f, 0.f, 0.f, 0.f};
      int rbase = (n * 16 + fr) * 128;
      int rsw = (fr & 7) << 4;
#pragma unroll
      for (int ks = 0; ks < 2; ++ks) {
        bf16x8 ak = *(const bf16x8*)(bK + rbase + ((ks * 64 + g * 16) ^ rsw));
        s[n] = __builtin_amdgcn_mfma_f32_16x16x32_bf16(ak, qf[ks], s[n], 0, 0, 0);
      }
    }
    __builtin_amdgcn_s_setprio(0);

    // mask (diagonal tile only) + row max
    float tm = -1e30f;
    if (jt == qt) {
#pragma unroll
      for (int n = 0; n < 4; ++n)
#pragma unroll
        for (int r = 0; r < 4; ++r) {
          if (n * 16 + g * 4 + r > qoff) s[n][r] = -1e30f;
          tm = fmaxf(tm, s[n][r]);
        }
    } else {
#pragma unroll
      for (int n = 0; n < 4; ++n)
#pragma unroll
        for (int r = 0; r < 4; ++r) tm = fmaxf(tm, s[n][r]);
    }
    tm = fmaxf(tm, __shfl_xor(tm, 16));
    tm = fmaxf(tm, __shfl_xor(tm, 32));
    // T13 defer-rescale
    if (!__all(tm <= m_r + 8.0f)) {
      float mn = fmaxf(m_r, tm);
      float sc = exp2_fast(m_r - mn);
      m_r = mn;
      l_r *= sc;
      float scj[4];
#pragma unroll
      for (int j = 0; j < 4; ++j) scj[j] = __shfl(sc, g * 4 + j);
#pragma unroll
      for (int nd = 0; nd < 4; ++nd)
#pragma unroll
        for (int j = 0; j < 4; ++j) acc[nd][j] *= scj[j];
    }
    // exp2 + sum + pack
    float rs = 0.f;
    u32 pw[4][2];
#pragma unroll
    for (int n = 0; n < 4; ++n) {
      float p0 = exp2_fast(s[n][0] - m_r);
      float p1 = exp2_fast(s[n][1] - m_r);
      float p2 = exp2_fast(s[n][2] - m_r);
      float p3 = exp2_fast(s[n][3] - m_r);
      rs += (p0 + p1) + (p2 + p3);
      pw[n][0] = cvt_pk(p0, p1);
      pw[n][1] = cvt_pk(p2, p3);
    }
    rs += __shfl_xor(rs, 16);
    rs += __shfl_xor(rs, 32);
    l_r += rs;
    // write P row (wave-private, in-wave DS ordering) + read PV A-frags
    bf16x8 pa[2];
    {
      char* base = (char*)lP + prow * 128;
#pragma unroll
      for (int n = 0; n < 4; ++n)
        *(u32x2v*)(base + ((32 * n + 8 * g) ^ psw)) = (u32x2v){pw[n][0], pw[n][1]};
#pragma unroll
      for (int ks = 0; ks < 2; ++ks)
        pa[ks] = *(const bf16x8*)(base + ((ks * 64 + g * 16) ^ psw));
    }
    // PV: acc[nd] += P x V^T rows
    __builtin_amdgcn_s_setprio(1);
#pragma unroll
    for (int nd = 0; nd < 4; ++nd) {
      int rbase = (nd * 16 + fr) * 128;
      int rsw = (fr & 7) << 4;
#pragma unroll
      for (int ks = 0; ks < 2; ++ks) {
        bf16x8 bv = *(const bf16x8*)(bV + rbase + ((ks * 64 + g * 16) ^ rsw));
        acc[nd] = __builtin_amdgcn_mfma_f32_16x16x32_bf16(pa[ks], bv, acc[nd], 0, 0, 0);
      }
    }
    __builtin_amdgcn_s_setprio(0);
    // commit next tile to the other buffer; single barrier per iter
    if (jt < qt) {
#pragma unroll
      for (int ps = 0; ps < 2; ++ps) {
        *(bf16x8*)((char*)lK[(jt + 1) & 1] + (ps * 32 + srow) * 128 + sswz) = rk[ps];
        *(bf16x8*)((char*)lV[(jt + 1) & 1] + (ps * 32 + srow) * 128 + sswz) = rv[ps];
      }
      __syncthreads();
    }
  }

  // epilogue: normalize, merge heads into AO [B,T,H] bf16
  const int b = bh >> 4, hh = bh & 15;
  float lj[4];
#pragma unroll
  for (int j = 0; j < 4; ++j) lj[j] = __shfl(l_r, g * 4 + j);
#pragma unroll
  for (int j = 0; j < 4; ++j) {
    float inv = 1.0f / lj[j];
    int qq = q0 + w * 16 + g * 4 + j;
    size_t base = (((size_t)b * Tt + qq) << 10) + hh * 64;
#pragma unroll
    for (int nd = 0; nd < 4; ++nd)
      AO[base + nd * 16 + fr] = f2b(acc[nd][j] * inv);
  }
}

extern "C" void kernel_launch(void* const* d_in, const int* in_sizes, int n_in,
                              void* d_out, int out_size, void* d_ws, size_t ws_size,
                              hipStream_t stream) {
  const float* q   = (const float*)d_in[0];
  const float* k   = (const float*)d_in[1];
  const float* v   = (const float*)d_in[2];
  // d_in[3] = mask (known causal tril; unused)
  const float* wq  = (const float*)d_in[4];
  const float* bq  = (const float*)d_in[5];
  const float* wk  = (const float*)d_in[6];
  const float* bk  = (const float*)d_in[7];
  const float* wv  = (const float*)d_in[8];
  const float* bv  = (const float*)d_in[9];
  const float* wo  = (const float*)d_in[10];
  const float* bo  = (const float*)d_in[11];

  char* ws = (char*)d_ws;
  const size_t SZB = (size_t)Bb * Tt * Hh * 2;  // 8.39 MB
  const size_t WB  = (size_t)Hh * Hh * 2;       // 2.10 MB
  u16* qb  = (u16*)(ws);
  u16* kb  = (u16*)(ws + SZB);
  u16* vb  = (u16*)(ws + 2 * SZB);
  u16* wqb = (u16*)(ws + 3 * SZB);
  u16* wkb = (u16*)(ws + 3 * SZB + WB);
  u16* wvb = (u16*)(ws + 3 * SZB + 2 * WB);
  u16* wob = (u16*)(ws + 3 * SZB + 3 * WB);
  u16* Qp  = (u16*)(ws + 3 * SZB + 4 * WB);
  u16* Kp  = (u16*)(ws + 4 * SZB + 4 * WB);
  u16* Vt  = (u16*)(ws + 5 * SZB + 4 * WB);
  u16* AO  = qb;   // reuse (qb dead after projections)

  const int N4_IN = (Bb * Tt * Hh) / 4;
  const int N4_W  = (Hh * Hh) / 4;
  cvt3_kernel<<<dim3(512, 3), 256, 0, stream>>>(q, k, v, qb, kb, vb, N4_IN);
  cvt4_kernel<<<dim3(128, 4), 256, 0, stream>>>(wq, wk, wv, wo, wqb, wkb, wvb, wob, N4_W);

  proj_qkv_kernel<<<dim3(1536), 256, 0, stream>>>(
      qb, kb, vb, wqb, wkb, wvb, bq, bk, bv, Qp, Kp, Vt);

  attn_kernel<<<dim3(1024), 256, 0, stream>>>(Qp, Kp, Vt, AO);

  gemm_out_kernel<<<dim3(512), 256, 0, stream>>>(
      AO, wob, bo, (float*)d_out);
}